// Round 3
// baseline (1063.267 us; speedup 1.0000x reference)
//
#include <hip/hip_runtime.h>
#include <stdint.h>

#define M_DIM 2048
#define K_DIM 8192
#define N_Q   8192
#define N_KV  1024
#define N_TOT (N_Q + 2 * N_KV)   // 10240
#define BM    128
#define BN    128
#define BK    32
#define NIT   (K_DIM / BK)       // 256 K-iterations

typedef __bf16 bf16x8 __attribute__((ext_vector_type(8)));
typedef __bf16 bf16x2 __attribute__((ext_vector_type(2)));
typedef float  f32x4  __attribute__((ext_vector_type(4)));

// XOR swizzle of the 16B k-chunk index by row: frag ds_read_b128 stay ~2-way (free per m136)
__device__ __forceinline__ uint32_t swz(uint32_t r) { return ((r >> 1) ^ (r >> 3)) & 3u; }

// f32 pair -> packed bf16x2 (RNE); pattern-matches v_cvt_pk_bf16_f32 on gfx950
__device__ __forceinline__ uint32_t pack_bf16(float lo, float hi) {
    bf16x2 v = { (__bf16)lo, (__bf16)hi };
    return __builtin_bit_cast(uint32_t, v);
}

__device__ __forceinline__ void async_copy16(const void* g, void* l) {
    __builtin_amdgcn_global_load_lds(
        (const __attribute__((address_space(1))) uint32_t*)g,
        (__attribute__((address_space(3))) uint32_t*)l, 16, 0, 0);
}

// ============================ Phase A kernels ============================

// x: f32 [M][K] -> bf16 [M][K] (pure convert, k-contiguous preserved)
__global__ __launch_bounds__(256) void cvt_x(const float* __restrict__ x,
                                             uint16_t* __restrict__ xb) {
    const size_t n4 = (size_t)M_DIM * K_DIM / 4;
    size_t i = (size_t)blockIdx.x * 256 + threadIdx.x;
    const size_t stride = (size_t)gridDim.x * 256;
    for (; i < n4; i += stride) {
        f32x4 v = ((const f32x4*)x)[i];
        uint2 w;
        w.x = pack_bf16(v.x, v.y);
        w.y = pack_bf16(v.z, v.w);
        ((uint2*)xb)[i] = w;
    }
}

// W: f32 [K][ldW] -> bf16 W^T [ldW][K] (64x64 tiles via padded LDS; both phases <=2-way banks)
__global__ __launch_bounds__(256) void transpose_w(const float* __restrict__ W,
                                                   uint16_t* __restrict__ WT,
                                                   int ldW) {
    __shared__ float sT[64][65];
    const uint32_t t  = threadIdx.x;
    const uint32_t n0 = blockIdx.x * 64;
    const uint32_t k0 = blockIdx.y * 64;

    // load: thread covers rows k0 + (t>>4) + 16i, cols n0 + (t&15)*4 .. +3
    const uint32_t kl = t >> 4, nn = (t & 15) * 4;
    #pragma unroll
    for (int i = 0; i < 4; ++i) {
        f32x4 v = *(const f32x4*)(W + (size_t)(k0 + kl + 16 * i) * ldW + n0 + nn);
        sT[kl + 16 * i][nn + 0] = v.x;
        sT[kl + 16 * i][nn + 1] = v.y;
        sT[kl + 16 * i][nn + 2] = v.z;
        sT[kl + 16 * i][nn + 3] = v.w;
    }
    __syncthreads();

    // store: thread owns output row n = t>>2, k-chunk (t&3)*16 .. +15 (32B = 2 x b128)
    const uint32_t n = t >> 2, kc = (t & 3) * 16;
    uint32_t d[8];
    #pragma unroll
    for (int j = 0; j < 8; ++j)
        d[j] = pack_bf16(sT[kc + 2 * j][n], sT[kc + 2 * j + 1][n]);
    uint16_t* op = WT + (size_t)(n0 + n) * K_DIM + k0 + kc;
    *(uint4*)(op)     = *(uint4*)&d[0];
    *(uint4*)(op + 8) = *(uint4*)&d[4];
}

// ============================ Phase B: bf16 GEMM (m97 structure) ============================

__global__ __launch_bounds__(256) void qkv_gemm_bf16(
    const uint16_t* __restrict__ xb,    // bf16 [M][K]
    const uint16_t* __restrict__ wt,    // bf16 [N_TOT][K]
    float* __restrict__ out)
{
    __shared__ __align__(16) uint16_t sA[BM * BK];   // [m][k], chunk-swizzled
    __shared__ __align__(16) uint16_t sB[BN * BK];   // [n][k], chunk-swizzled

    const uint32_t tid    = threadIdx.x;
    const uint32_t bid    = blockIdx.x;
    const uint32_t mt_blk = bid & 15;     // 16 consecutive blocks share one W^T row slab
    const uint32_t nt_blk = bid >> 4;     // 80 n-tiles == head index across q|k|v concat
    const uint32_t m0     = mt_blk * BM;
    const uint32_t n0     = nt_blk * BN;

    // ---- DMA staging maps: chunk c (0..511): row r = c>>2, phys chunk p = c&3 holds
    //      logical kc = p ^ swz(r). LDS side is lane-contiguous (base + lane*16). ----
    const uint32_t c0 = tid, c1 = tid + 256;
    const uint32_t r0 = c0 >> 2, r1 = c1 >> 2;
    const uint32_t kc0 = (c0 & 3) ^ swz(r0);
    const uint32_t kc1 = (c1 & 3) ^ swz(r1);
    const uint16_t* agp0 = xb + (size_t)(m0 + r0) * K_DIM + kc0 * 8;
    const uint16_t* agp1 = xb + (size_t)(m0 + r1) * K_DIM + kc1 * 8;
    const uint16_t* bgp0 = wt + (size_t)(n0 + r0) * K_DIM + kc0 * 8;
    const uint16_t* bgp1 = wt + (size_t)(n0 + r1) * K_DIM + kc1 * 8;
    uint16_t* alds0 = sA + c0 * 8;
    uint16_t* alds1 = sA + c1 * 8;
    uint16_t* blds0 = sB + c0 * 8;
    uint16_t* blds1 = sB + c1 * 8;

    // ---- wave / lane decomposition (2x2 waves, each 64x64) ----
    const uint32_t lane = tid & 63;
    const uint32_t wid  = tid >> 6;
    const uint32_t wm   = (wid >> 1) * 64;
    const uint32_t wn   = (wid & 1) * 64;
    const uint32_t l15  = lane & 15;
    const uint32_t quad = lane >> 4;

    f32x4 acc[4][4] = {};

    // fragment read offsets (ushort units): row*BK + (quad^swz(row))*8
    uint32_t a_off[4], b_off[4];
    #pragma unroll
    for (int t = 0; t < 4; ++t) {
        uint32_t ar = wm + t * 16 + l15;
        a_off[t] = ar * BK + ((quad ^ swz(ar)) * 8);
        uint32_t br = wn + t * 16 + l15;
        b_off[t] = br * BK + ((quad ^ swz(br)) * 8);
    }

    for (uint32_t kt = 0; kt < NIT; ++kt) {
        __syncthreads();   // prior iter's frag reads done -> LDS reusable

        const size_t ko = (size_t)kt * BK;
        async_copy16(agp0 + ko, alds0);
        async_copy16(agp1 + ko, alds1);
        async_copy16(bgp0 + ko, blds0);
        async_copy16(bgp1 + ko, blds1);

        __syncthreads();   // barrier drains vmcnt -> LDS tiles complete

        bf16x8 af[4], bf[4];
        #pragma unroll
        for (int t = 0; t < 4; ++t) {
            af[t] = *(const bf16x8*)(sA + a_off[t]);
            bf[t] = *(const bf16x8*)(sB + b_off[t]);
        }
        #pragma unroll
        for (int mt = 0; mt < 4; ++mt)
            #pragma unroll
            for (int nt = 0; nt < 4; ++nt)
                acc[mt][nt] = __builtin_amdgcn_mfma_f32_16x16x32_bf16(
                    af[mt], bf[nt], acc[mt][nt], 0, 0, 0);
    }

    // ---- epilogue: head nt_blk, rows m0..m0+127, dims 0..127 (contiguous f32 slab) ----
    // C/D layout: col = lane&15, row = quad*4 + reg (m89/m91 verified)
    float* op = out + (size_t)nt_blk * M_DIM * 128 + (size_t)m0 * 128;
    #pragma unroll
    for (int mt = 0; mt < 4; ++mt) {
        #pragma unroll
        for (int r = 0; r < 4; ++r) {
            uint32_t row = wm + mt * 16 + quad * 4 + r;
            #pragma unroll
            for (int nt = 0; nt < 4; ++nt) {
                uint32_t col = wn + nt * 16 + l15;
                op[(size_t)row * 128 + col] = acc[mt][nt][r];
            }
        }
    }
}

// ============================ Fallback: round-2 kernel (proven, no ws) ============================

__global__ __launch_bounds__(256) void qkv_gemm_fb(
    const float* __restrict__ x,
    const float* __restrict__ wq,
    const float* __restrict__ wk,
    const float* __restrict__ wv,
    float* __restrict__ out)
{
    __shared__ __align__(16) uint16_t sA[BM * BK];
    __shared__ __align__(16) uint16_t sB[BN * BK];
    uint32_t* sAu = (uint32_t*)sA;
    uint32_t* sBu = (uint32_t*)sB;

    const uint32_t tid    = threadIdx.x;
    const uint32_t bid    = blockIdx.x;
    const uint32_t mt_blk = bid & 15;
    const uint32_t nt_blk = bid >> 4;
    const uint32_t m0     = mt_blk * BM;

    const size_t QSZ = (size_t)64 * M_DIM * 128;
    const size_t KSZ = (size_t)8  * M_DIM * 128;
    const float* Wsel;
    uint32_t ldW, col0;
    size_t obase;
    if (nt_blk < 64)      { Wsel = wq; ldW = N_Q;  col0 = nt_blk * 128;
                            obase = (size_t)nt_blk * M_DIM * 128; }
    else if (nt_blk < 72) { Wsel = wk; ldW = N_KV; col0 = (nt_blk - 64) * 128;
                            obase = QSZ + (size_t)(nt_blk - 64) * M_DIM * 128; }
    else                  { Wsel = wv; ldW = N_KV; col0 = (nt_blk - 72) * 128;
                            obase = QSZ + KSZ + (size_t)(nt_blk - 72) * M_DIM * 128; }

    const float* agp = x + (size_t)(m0 + (tid >> 3)) * K_DIM + (tid & 7) * 4;
    uint32_t a_wr[4];
    #pragma unroll
    for (int i = 0; i < 4; ++i) {
        uint32_t r = i * 32 + (tid >> 3);
        a_wr[i] = r * 16 + ((((tid >> 1) & 3) ^ swz(r)) * 4) + (tid & 1) * 2;
    }

    const uint32_t bk  = (tid >> 4) * 2;
    const uint32_t bn0 = (tid & 15) * 8;
    const float* bgp = Wsel + (size_t)bk * ldW + col0 + bn0;
    const uint32_t bkc = bk >> 3;
    const uint32_t bkd = (bk & 7) >> 1;

    f32x4 apre[4], bpre[4];
    #pragma unroll
    for (int i = 0; i < 4; ++i) apre[i] = *(const f32x4*)(agp + (size_t)i * 32 * K_DIM);
    bpre[0] = *(const f32x4*)(bgp);
    bpre[1] = *(const f32x4*)(bgp + 4);
    bpre[2] = *(const f32x4*)(bgp + ldW);
    bpre[3] = *(const f32x4*)(bgp + ldW + 4);

    const uint32_t lane = tid & 63;
    const uint32_t wid  = tid >> 6;
    const uint32_t wm   = (wid >> 1) * 64;
    const uint32_t wn   = (wid & 1) * 64;
    const uint32_t l15  = lane & 15;
    const uint32_t quad = lane >> 4;

    f32x4 acc[4][4] = {};

    uint32_t a_off[4], b_off[4];
    #pragma unroll
    for (int t = 0; t < 4; ++t) {
        uint32_t ar = wm + t * 16 + l15;
        a_off[t] = ar * BK + ((quad ^ swz(ar)) * 8);
        uint32_t br = wn + t * 16 + l15;
        b_off[t] = br * BK + ((quad ^ swz(br)) * 8);
    }

    const float* agp_n = agp + BK;
    const float* bgp_n = bgp + (size_t)BK * ldW;

    for (uint32_t kt = 0; kt < NIT; ++kt) {
        __syncthreads();

        #pragma unroll
        for (int i = 0; i < 4; ++i) {
            uint2 w;
            w.x = pack_bf16(apre[i].x, apre[i].y);
            w.y = pack_bf16(apre[i].z, apre[i].w);
            *(uint2*)&sAu[a_wr[i]] = w;
        }
        {
            const float* pk0 = (const float*)&bpre[0];
            const float* pk1 = (const float*)&bpre[2];
            #pragma unroll
            for (int j = 0; j < 8; ++j) {
                uint32_t n = bn0 + j;
                sBu[n * 16 + ((bkc ^ swz(n)) * 4) + bkd] = pack_bf16(pk0[j], pk1[j]);
            }
        }

        if (kt + 1 < NIT) {
            #pragma unroll
            for (int i = 0; i < 4; ++i) apre[i] = *(const f32x4*)(agp_n + (size_t)i * 32 * K_DIM);
            bpre[0] = *(const f32x4*)(bgp_n);
            bpre[1] = *(const f32x4*)(bgp_n + 4);
            bpre[2] = *(const f32x4*)(bgp_n + ldW);
            bpre[3] = *(const f32x4*)(bgp_n + ldW + 4);
            agp_n += BK;
            bgp_n += (size_t)BK * ldW;
        }

        __syncthreads();

        bf16x8 af[4], bf[4];
        #pragma unroll
        for (int t = 0; t < 4; ++t) {
            af[t] = *(const bf16x8*)(sA + a_off[t]);
            bf[t] = *(const bf16x8*)(sB + b_off[t]);
        }
        #pragma unroll
        for (int mt = 0; mt < 4; ++mt)
            #pragma unroll
            for (int nt = 0; nt < 4; ++nt)
                acc[mt][nt] = __builtin_amdgcn_mfma_f32_16x16x32_bf16(
                    af[mt], bf[nt], acc[mt][nt], 0, 0, 0);
    }

    float* op = out + obase + (size_t)m0 * 128;
    #pragma unroll
    for (int mt = 0; mt < 4; ++mt) {
        #pragma unroll
        for (int r = 0; r < 4; ++r) {
            uint32_t row = wm + mt * 16 + quad * 4 + r;
            #pragma unroll
            for (int nt = 0; nt < 4; ++nt) {
                uint32_t col = wn + nt * 16 + l15;
                op[(size_t)row * 128 + col] = acc[mt][nt][r];
            }
        }
    }
}

// ============================ launch ============================

extern "C" void kernel_launch(void* const* d_in, const int* in_sizes, int n_in,
                              void* d_out, int out_size, void* d_ws, size_t ws_size,
                              hipStream_t stream) {
    const float* x  = (const float*)d_in[0];
    const float* wq = (const float*)d_in[1];
    const float* wk = (const float*)d_in[2];
    const float* wv = (const float*)d_in[3];
    float* out = (float*)d_out;

    const size_t xb_bytes = (size_t)M_DIM * K_DIM * 2;           // 32 MB
    const size_t wt_bytes = (size_t)N_TOT * K_DIM * 2;           // 160 MB
    if (ws_size >= xb_bytes + wt_bytes) {
        uint16_t* xb = (uint16_t*)d_ws;
        uint16_t* wt = (uint16_t*)((char*)d_ws + xb_bytes);
        // Phase A
        cvt_x<<<dim3(2048), dim3(256), 0, stream>>>(x, xb);
        transpose_w<<<dim3(N_Q / 64, K_DIM / 64), dim3(256), 0, stream>>>(wq, wt, N_Q);
        transpose_w<<<dim3(N_KV / 64, K_DIM / 64), dim3(256), 0, stream>>>(
            wk, wt + (size_t)N_Q * K_DIM, N_KV);
        transpose_w<<<dim3(N_KV / 64, K_DIM / 64), dim3(256), 0, stream>>>(
            wv, wt + (size_t)(N_Q + N_KV) * K_DIM, N_KV);
        // Phase B
        qkv_gemm_bf16<<<dim3((M_DIM / BM) * (N_TOT / BN)), dim3(256), 0, stream>>>(xb, wt, out);
    } else {
        qkv_gemm_fb<<<dim3((M_DIM / BM) * (N_TOT / BN)), dim3(256), 0, stream>>>(
            x, wq, wk, wv, out);
    }
}